// Round 5
// baseline (308.020 us; speedup 1.0000x reference)
//
#include <hip/hip_runtime.h>

// Problem constants
#define BATCH 8
#define T_IN  262144
#define S_OUT 131072          // (T + 2*2 - 5)/2 + 1
#define EDIM  128
#define PDIM  64
#define KW    5
#define TILE_S 256            // s rows per block (4 subtiles of 64)
#define TILES_PER_B (S_OUT / TILE_S)   // 512

typedef __attribute__((ext_vector_type(8))) short short8;
typedef __attribute__((ext_vector_type(4))) float f32x4;
typedef __attribute__((ext_vector_type(4))) int   i32x4;

// One v_cvt_pk_bf16_f32 (no builtin on gfx950 — inline asm per T12 recipe):
// packs (a,b) -> [lo16 = bf16(a) | hi16 = bf16(b)], round-to-nearest-even
__device__ __forceinline__ int pk_bf16(float a, float b) {
    int r;
    asm("v_cvt_pk_bf16_f32 %0, %1, %2" : "=v"(r) : "v"(a), "v"(b));
    return r;
}

__global__ __launch_bounds__(256, 4)
void mm_encoder_kernel(const float* __restrict__ audio,
                       const float* __restrict__ conv_w,
                       const float* __restrict__ conv_b,
                       const float* __restrict__ lin_w,
                       const float* __restrict__ lin_b,
                       float* __restrict__ out) {
    __shared__ __align__(16) float xs[528];                 // audio window for whole block (520 used)
    __shared__ __align__(16) short fa[64][136];             // bf16 feats subtile (+8 pad)
    __shared__ __align__(16) short wb[16][64][8];           // swizzled B fragments [kt*4+nt][lane][j]

    const int tid = threadIdx.x;
    const int b   = blockIdx.x >> 9;                        // 512 tiles per batch
    const int t0  = (blockIdx.x & (TILES_PER_B - 1)) << 8;

    const float* xb = audio + (long)b * T_IN;
    const int base  = 2 * t0 - 4;                           // first sample staged (float4-aligned)

    // ---- Stage audio window [base, base+520) into LDS, coalesced float4 ----
    // Only the first/last tile of each batch needs clamping (block-uniform branch).
    if (tid < 130) {
        const int i0 = tid << 2;
        if (base >= 0 && base + 520 <= T_IN) {
            *(f32x4*)&xs[i0] = *(const f32x4*)(xb + base + i0);
        } else {
            f32x4 v;
            #pragma unroll
            for (int j = 0; j < 4; ++j) {
                int g = base + i0 + j;
                v[j] = ((unsigned)g < (unsigned)T_IN) ? xb[g] : 0.0f;
            }
            *(f32x4*)&xs[i0] = v;
        }
    }

    // ---- Stage swizzled bf16 W fragments ONCE per block (float4 loads + cvt_pk) ----
    // p = nt*16 + (l&15), e = kt*32 + (l>>4)*8 + j
    for (int c = tid; c < 1024; c += 256) {
        int kt = c >> 8;
        int nt = (c >> 6) & 3;
        int l  = c & 63;
        int p  = nt * 16 + (l & 15);
        int e0 = kt * 32 + ((l >> 4) << 3);
        const float* src = lin_w + p * EDIM + e0;
        f32x4 v0 = *(const f32x4*)(src);
        f32x4 v1 = *(const f32x4*)(src + 4);
        i32x4 w;
        w[0] = pk_bf16(v0[0], v0[1]);
        w[1] = pk_bf16(v0[2], v0[3]);
        w[2] = pk_bf16(v1[0], v1[1]);
        w[3] = pk_bf16(v1[2], v1[3]);
        *(i32x4*)&wb[(kt << 2) + nt][l][0] = w;
    }

    const int wv   = tid >> 6;
    const int lane = tid & 63;
    const int quad = lane >> 4;
    const int m    = lane & 15;
    const int e    = lane << 1;

    // conv weights for this thread's e-pair (L1/L2-resident after first block/CU)
    float w0[KW], w1[KW];
    #pragma unroll
    for (int k = 0; k < KW; ++k) {
        w0[k] = conv_w[e * KW + k];
        w1[k] = conv_w[(e + 1) * KW + k];
    }
    const float cb0 = conv_b[e];
    const float cb1 = conv_b[e + 1];
    float lbv[4];
    #pragma unroll
    for (int nt = 0; nt < 4; ++nt) lbv[nt] = lin_b[nt * 16 + m];

    __syncthreads();   // xs + wb visible to all waves; the ONLY barrier

    // No explicit lgkmcnt drains anywhere below:
    //  - fa RAW is same-wave (each wave reads only its own rows); the LDS unit
    //    processes one wave's DS ops in order, so the compiler's automatic
    //    lgkmcnt before first use is sufficient and better-placed (all 16
    //    writes + 20 reads in flight, ONE wait — vs drain-then-serial-reads).
    //  - fa reads go through __builtin_memcpy (char aliasing), so the compiler
    //    cannot TBAA-reorder them against the int writes.
    #pragma unroll
    for (int st = 0; st < 4; ++st) {
        const int srowL = st * 64 + wv * 16;   // local row base (this wave's 16 rows)

        // ---- Audio window from LDS: 10 broadcast ds_read_b128, no clamp logic ----
        float x[40];
        #pragma unroll
        for (int i = 0; i < 10; ++i)
            *(f32x4*)&x[i * 4] = *(const f32x4*)&xs[2 * srowL + i * 4];

        // ---- Conv + bias + relu, register sliding window, cvt_pk packing ----
        #pragma unroll
        for (int r = 0; r < 16; ++r) {
            float a0 = cb0, a1 = cb1;
            #pragma unroll
            for (int k = 0; k < KW; ++k) {
                a0 = fmaf(w0[k], x[2 * r + k + 2], a0);
                a1 = fmaf(w1[k], x[2 * r + k + 2], a1);
            }
            a0 = fmaxf(a0, 0.0f);
            a1 = fmaxf(a1, 0.0f);
            int pr = pk_bf16(a0, a1);
            __builtin_memcpy(&fa[wv * 16 + r][e], &pr, 4);   // ds_write_b32
        }

        // ---- MFMA: 16 s x 64 p, K=128; lin_b folded into C-init ----
        // C/D layout: col = lane&15 (p), row = quad*4 + reg (s)
        f32x4 acc[4];
        #pragma unroll
        for (int nt = 0; nt < 4; ++nt) {
            acc[nt][0] = lbv[nt]; acc[nt][1] = lbv[nt];
            acc[nt][2] = lbv[nt]; acc[nt][3] = lbv[nt];
        }
        #pragma unroll
        for (int kt = 0; kt < 4; ++kt) {
            short8 a;
            __builtin_memcpy(&a, &fa[wv * 16 + m][kt * 32 + quad * 8], 16);  // ds_read_b128
            #pragma unroll
            for (int nt = 0; nt < 4; ++nt) {
                short8 bf = *(const short8*)&wb[(kt << 2) + nt][lane][0];
                acc[nt] = __builtin_amdgcn_mfma_f32_16x16x32_bf16(a, bf, acc[nt], 0, 0, 0);
            }
        }

        // ---- Epilogue: direct stores (R4 proved store shape is value-neutral;
        //      this variant has the shortest dependency chain and no DS ops) ----
        const int srow0 = t0 + srowL;
        float* po = out + (long)b * S_OUT * PDIM + (long)(srow0 + quad * 4) * PDIM + m;
        #pragma unroll
        for (int nt = 0; nt < 4; ++nt) {
            #pragma unroll
            for (int r = 0; r < 4; ++r) {
                po[r * PDIM + nt * 16] = acc[nt][r];
            }
        }
    }
}

extern "C" void kernel_launch(void* const* d_in, const int* in_sizes, int n_in,
                              void* d_out, int out_size, void* d_ws, size_t ws_size,
                              hipStream_t stream) {
    const float* audio  = (const float*)d_in[0];
    const float* conv_w = (const float*)d_in[1];
    const float* conv_b = (const float*)d_in[2];
    const float* lin_w  = (const float*)d_in[3];
    const float* lin_b  = (const float*)d_in[4];
    float* out = (float*)d_out;

    // 8 batches * 512 tiles = 4096 blocks
    dim3 grid(BATCH * TILES_PER_B);
    dim3 block(256);
    hipLaunchKernelGGL(mm_encoder_kernel, grid, block, 0, stream,
                       audio, conv_w, conv_b, lin_w, lin_b, out);
}

// Round 7
// 281.125 us; speedup vs baseline: 1.0957x; 1.0957x over previous
//
#include <hip/hip_runtime.h>

// Problem constants
#define BATCH 8
#define T_IN  262144
#define S_OUT 131072          // (T + 2*2 - 5)/2 + 1
#define EDIM  128
#define PDIM  64
#define KW    5
#define TILE_S 256            // s rows per tile (4 subtiles of 64)
#define TILES_PER_B (S_OUT / TILE_S)     // 512
#define TILES_TOTAL (BATCH * TILES_PER_B)// 4096
#define TPB 4                            // tiles per block (persistent-ish blocks)
#define GRID_BLOCKS (TILES_TOTAL / TPB)  // 1024 = 4 blocks/CU x 256 CUs, fully resident

typedef __attribute__((ext_vector_type(8))) short short8;
typedef __attribute__((ext_vector_type(4))) float f32x4;
typedef __attribute__((ext_vector_type(4))) int   i32x4;

// One v_cvt_pk_bf16_f32 (no builtin on gfx950 — inline asm per T12 recipe):
// packs (a,b) -> [lo16 = bf16(a) | hi16 = bf16(b)], round-to-nearest-even
__device__ __forceinline__ int pk_bf16(float a, float b) {
    int r;
    asm("v_cvt_pk_bf16_f32 %0, %1, %2" : "=v"(r) : "v"(a), "v"(b));
    return r;
}

__global__ __launch_bounds__(256, 4)
void mm_encoder_kernel(const float* __restrict__ audio,
                       const float* __restrict__ conv_w,
                       const float* __restrict__ conv_b,
                       const float* __restrict__ lin_w,
                       const float* __restrict__ lin_b,
                       float* __restrict__ out) {
    __shared__ __align__(16) float xs[528];                 // audio window for current tile (520 used)
    __shared__ __align__(16) short fa[64][136];             // bf16 feats subtile (+8 pad)
    __shared__ __align__(16) short wb[16][64][8];           // swizzled B fragments [kt*4+nt][lane][j]

    const int tid = threadIdx.x;
    const int g0  = blockIdx.x * TPB;                       // first global tile index
    const int b   = g0 >> 9;                                // 512 tiles/batch; g0..g0+3 same batch
    const float* xb = audio + (long)b * T_IN;

    // ---- Stage swizzled bf16 W fragments ONCE per block (float4 loads + cvt_pk) ----
    // p = nt*16 + (l&15), e = kt*32 + (l>>4)*8 + j
    for (int c = tid; c < 1024; c += 256) {
        int kt = c >> 8;
        int nt = (c >> 6) & 3;
        int l  = c & 63;
        int p  = nt * 16 + (l & 15);
        int e0 = kt * 32 + ((l >> 4) << 3);
        const float* src = lin_w + p * EDIM + e0;
        f32x4 v0 = *(const f32x4*)(src);
        f32x4 v1 = *(const f32x4*)(src + 4);
        i32x4 w;
        w[0] = pk_bf16(v0[0], v0[1]);
        w[1] = pk_bf16(v0[2], v0[3]);
        w[2] = pk_bf16(v1[0], v1[1]);
        w[3] = pk_bf16(v1[2], v1[3]);
        *(i32x4*)&wb[(kt << 2) + nt][l][0] = w;
    }

    const int wv   = tid >> 6;
    const int lane = tid & 63;
    const int quad = lane >> 4;
    const int m    = lane & 15;
    const int e    = lane << 1;

    // conv weights for this thread's e-pair (loaded once per block now)
    float w0[KW], w1[KW];
    #pragma unroll
    for (int k = 0; k < KW; ++k) {
        w0[k] = conv_w[e * KW + k];
        w1[k] = conv_w[(e + 1) * KW + k];
    }
    const float cb0 = conv_b[e];
    const float cb1 = conv_b[e + 1];
    float lbv[4];
    #pragma unroll
    for (int nt = 0; nt < 4; ++nt) lbv[nt] = lin_b[nt * 16 + m];

    // ---- Audio window loader: [2*t0-4, +520) for a tile, clamped at batch edges ----
    // Returns this thread's float4 chunk (tid<130 active).
    auto loadx = [&](int t0) -> f32x4 {
        f32x4 r = {0.f, 0.f, 0.f, 0.f};
        const int base = 2 * t0 - 4;
        if (tid < 130) {
            const int i0 = tid << 2;
            if (base >= 0 && base + 520 <= T_IN) {
                r = *(const f32x4*)(xb + base + i0);
            } else {
                #pragma unroll
                for (int j = 0; j < 4; ++j) {
                    int g = base + i0 + j;
                    r[j] = ((unsigned)g < (unsigned)T_IN) ? xb[g] : 0.0f;
                }
            }
        }
        return r;
    };

    // Prefetch tile 0 audio, stage it, single barrier covers wb + xs.
    f32x4 vnext = loadx((g0 & 511) << 8);
    if (tid < 130) *(f32x4*)&xs[tid << 2] = vnext;
    __syncthreads();

    #pragma unroll 1
    for (int it = 0; it < TPB; ++it) {
        const int t0 = ((g0 + it) & 511) << 8;              // row base within batch

        // Prefetch NEXT tile's audio into registers now; vmcnt waits only at the
        // xs-write after the end-of-tile barrier -> HBM latency hides under the
        // 4 subtiles of conv+MFMA below (T14 issue-early / write-late).
        if (it + 1 < TPB) vnext = loadx(((g0 + it + 1) & 511) << 8);

        // No explicit lgkmcnt drains: fa RAW is same-wave (in-order DS per wave;
        // compiler auto-waitcnt before first use), and fa accesses go through
        // __builtin_memcpy so TBAA can't reorder them against the writes.
        #pragma unroll
        for (int st = 0; st < 4; ++st) {
            const int srowL = st * 64 + wv * 16;   // this wave's 16 rows

            // ---- Audio window from LDS: 10 broadcast ds_read_b128 ----
            float x[40];
            #pragma unroll
            for (int i = 0; i < 10; ++i)
                *(f32x4*)&x[i * 4] = *(const f32x4*)&xs[2 * srowL + i * 4];

            // ---- Conv + bias + relu, register sliding window, cvt_pk packing ----
            #pragma unroll
            for (int r = 0; r < 16; ++r) {
                float a0 = cb0, a1 = cb1;
                #pragma unroll
                for (int k = 0; k < KW; ++k) {
                    a0 = fmaf(w0[k], x[2 * r + k + 2], a0);
                    a1 = fmaf(w1[k], x[2 * r + k + 2], a1);
                }
                a0 = fmaxf(a0, 0.0f);
                a1 = fmaxf(a1, 0.0f);
                int pr = pk_bf16(a0, a1);
                __builtin_memcpy(&fa[wv * 16 + r][e], &pr, 4);   // ds_write_b32
            }

            // ---- MFMA: 16 s x 64 p, K=128; lin_b folded into C-init ----
            // C/D layout: col = lane&15 (p), row = quad*4 + reg (s)
            f32x4 acc[4];
            #pragma unroll
            for (int nt = 0; nt < 4; ++nt) {
                acc[nt][0] = lbv[nt]; acc[nt][1] = lbv[nt];
                acc[nt][2] = lbv[nt]; acc[nt][3] = lbv[nt];
            }
            #pragma unroll
            for (int kt = 0; kt < 4; ++kt) {
                short8 a;
                __builtin_memcpy(&a, &fa[wv * 16 + m][kt * 32 + quad * 8], 16); // ds_read_b128
                #pragma unroll
                for (int nt = 0; nt < 4; ++nt) {
                    short8 bf = *(const short8*)&wb[(kt << 2) + nt][lane][0];
                    acc[nt] = __builtin_amdgcn_mfma_f32_16x16x32_bf16(a, bf, acc[nt], 0, 0, 0);
                }
            }

            // ---- Epilogue: direct stores (R4 proved store shape value-neutral) ----
            const int srow0 = t0 + srowL;
            float* po = out + (long)b * S_OUT * PDIM + (long)(srow0 + quad * 4) * PDIM + m;
            #pragma unroll
            for (int nt = 0; nt < 4; ++nt) {
                #pragma unroll
                for (int r = 0; r < 4; ++r) {
                    po[r * PDIM + nt * 16] = acc[nt][r];
                }
            }
        }

        // ---- Rotate xs to the prefetched next tile ----
        if (it + 1 < TPB) {
            __syncthreads();                       // all waves done reading xs
            if (tid < 130) *(f32x4*)&xs[tid << 2] = vnext;   // vmcnt waits here
            __syncthreads();                       // xs(it+1) visible
        }
    }
}

extern "C" void kernel_launch(void* const* d_in, const int* in_sizes, int n_in,
                              void* d_out, int out_size, void* d_ws, size_t ws_size,
                              hipStream_t stream) {
    const float* audio  = (const float*)d_in[0];
    const float* conv_w = (const float*)d_in[1];
    const float* conv_b = (const float*)d_in[2];
    const float* lin_w  = (const float*)d_in[3];
    const float* lin_b  = (const float*)d_in[4];
    float* out = (float*)d_out;

    // 1024 blocks x 4 tiles each = 4096 tiles; exactly 4 blocks/CU resident
    dim3 grid(GRID_BLOCKS);
    dim3 block(256);
    hipLaunchKernelGGL(mm_encoder_kernel, grid, block, 0, stream,
                       audio, conv_w, conv_b, lin_w, lin_b, out);
}